// Round 1
// baseline (1691.736 us; speedup 1.0000x reference)
//
#include <hip/hip_runtime.h>
#include <math.h>

// ---------------- problem constants ----------------
#define LAYERS 2
#define DMODEL 256
#define NHEAD  8
#define DHEAD  32
#define FF     512
#define KNB    9
#define MB     4
#define G1D    40
#define G2D    40
#define NTGT   2048
#define NCTX   1600          // G1D*G2D
#define RC     (MB*NCTX)     // 6400 grid rows
#define RT     (MB*NTGT)     // 8192 target rows

// ---------------- workspace layout (float offsets) ----------------
#define ZC_OFF    0                         // 1,638,400 f  : zc state
#define H_OFF     1638400                   // 2,097,152 f  : LN output (max RT rows)
#define QKV_OFF   (H_OFF + 2097152)         // 4,915,200 f  : qkv / kv_grid / ffn-mid (aliased)
#define Q_OFF     (QKV_OFF + 4915200)       // 2,097,152 f  : CA q
#define O_OFF     (Q_OFF + 2097152)         // 2,097,152 f  : attention out
#define IDX_OFF   (O_OFF + 2097152)         // 73,728 int
#define MASK_OFF  (IDX_OFF + 73728)         // 73,728 f
#define WS_FLOATS (MASK_OFF + 73728)        // 12,992,512 f = ~52 MB

static __device__ __forceinline__ float gelu_f(float x){
  // jax.nn.gelu approximate=True (tanh form)
  float t = tanhf(0.7978845608028654f * (x + 0.044715f * x * x * x));
  return 0.5f * x * (1.0f + t);
}

// ---------------- utility: vectorized copy ----------------
__global__ void copy_kernel(const float* __restrict__ src, float* __restrict__ dst, int n4){
  int i = blockIdx.x * blockDim.x + threadIdx.x;
  if (i < n4) ((float4*)dst)[i] = ((const float4*)src)[i];
}

// ---------------- nearest-grid-neighbour index/mask precompute ----------------
__global__ void nn_idx_kernel(const float* __restrict__ xc, const float* __restrict__ xt,
                              int* __restrict__ idx, float* __restrict__ mask){
  int g = blockIdx.x * blockDim.x + threadIdx.x;  // m*NTGT + t
  if (g >= MB * NTGT) return;
  int m = g >> 11;  // / NTGT
  float x0 = xt[(size_t)g * 2 + 0];
  float x1 = xt[(size_t)g * 2 + 1];
  const float* xcm = xc + (size_t)m * G1D * G2D * 2;
  // ax0[i] = xc[m,i,0,0]  (stride G2D*2 = 80); ax1[j] = xc[m,0,j,1]
  int n0 = 0; float b0 = 1e30f;
  for (int i = 0; i < G1D; i++){
    float d = fabsf(x0 - xcm[i * (G2D * 2)]);
    if (d < b0){ b0 = d; n0 = i; }   // strict < keeps first occurrence (argmin semantics)
  }
  int n1 = 0; float b1 = 1e30f;
  for (int j = 0; j < G2D; j++){
    float d = fabsf(x1 - xcm[j * 2 + 1]);
    if (d < b1){ b1 = d; n1 = j; }
  }
  #pragma unroll
  for (int a = 0; a < 3; a++){
    int r0 = n0 + a - 1;
    bool v0 = (r0 >= 0) && (r0 < G1D);
    int i0 = min(max(r0, 0), G1D - 1);
    #pragma unroll
    for (int b = 0; b < 3; b++){
      int r1 = n1 + b - 1;
      bool v1 = (r1 >= 0) && (r1 < G2D);
      int i1 = min(max(r1, 0), G2D - 1);
      idx [(size_t)g * KNB + a * 3 + b] = i0 * G2D + i1;
      mask[(size_t)g * KNB + a * 3 + b] = (v0 && v1) ? 1.0f : 0.0f;
    }
  }
}

// ---------------- LayerNorm: one wave per 256-wide row ----------------
__global__ __launch_bounds__(256)
void ln_kernel(const float* __restrict__ x, const float* __restrict__ gb,
               float* __restrict__ y, int rows){
  int gw   = blockIdx.x * 4 + (threadIdx.x >> 6);  // wave id = row
  int lane = threadIdx.x & 63;
  if (gw >= rows) return;
  const float* xr = x + (size_t)gw * DMODEL;
  int d0 = lane * 4;
  float4 xv = *(const float4*)(xr + d0);
  float s = xv.x + xv.y + xv.z + xv.w;
  #pragma unroll
  for (int off = 32; off > 0; off >>= 1) s += __shfl_xor(s, off);
  float mu = s * (1.0f / DMODEL);
  float dx0 = xv.x - mu, dx1 = xv.y - mu, dx2 = xv.z - mu, dx3 = xv.w - mu;
  float v = dx0*dx0 + dx1*dx1 + dx2*dx2 + dx3*dx3;
  #pragma unroll
  for (int off = 32; off > 0; off >>= 1) v += __shfl_xor(v, off);
  float rs = rsqrtf(v * (1.0f / DMODEL) + 1e-5f);
  float4 g = *(const float4*)(gb + d0);
  float4 b = *(const float4*)(gb + DMODEL + d0);
  float4 o;
  o.x = dx0 * rs * g.x + b.x;
  o.y = dx1 * rs * g.y + b.y;
  o.z = dx2 * rs * g.z + b.z;
  o.w = dx3 * rs * g.w + b.w;
  *(float4*)(y + (size_t)gw * DMODEL + d0) = o;
}

// ---------------- tiled fp32 GEMM: C[R,N] = A[R,K] @ W[K,N] (+bias)(+gelu)(+res) ----------------
// flags: 1 = bias, 2 = gelu, 4 = residual add (res same shape as C)
#define BM 64
#define BN 64
#define BK 16
__global__ __launch_bounds__(256)
void gemm_kernel(const float* __restrict__ A, const float* __restrict__ W,
                 const float* __restrict__ bias, const float* __restrict__ res,
                 float* __restrict__ C, int R, int K, int N, int flags){
  __shared__ float As[BK][BM + 4];   // +4 pad: scalar transpose writes 2-way max
  __shared__ float Bs[BK][BN + 4];
  int tid = threadIdx.x;
  int tx = tid & 15, ty = tid >> 4;
  int r0 = blockIdx.y * BM, c0 = blockIdx.x * BN;
  int arow = tid >> 2, ak = (tid & 3) * 4;      // A: 64 rows x 16 k, float4 per thread
  int bkk  = tid >> 4, bcol = (tid & 15) * 4;   // W: 16 k x 64 cols, float4 per thread
  float acc[4][4] = {};
  for (int k0 = 0; k0 < K; k0 += BK){
    float4 av = *(const float4*)(A + (size_t)(r0 + arow) * K + k0 + ak);
    As[ak + 0][arow] = av.x; As[ak + 1][arow] = av.y;
    As[ak + 2][arow] = av.z; As[ak + 3][arow] = av.w;
    float4 bv = *(const float4*)(W + (size_t)(k0 + bkk) * N + c0 + bcol);
    *(float4*)&Bs[bkk][bcol] = bv;
    __syncthreads();
    #pragma unroll
    for (int kk = 0; kk < BK; kk++){
      float4 a = *(const float4*)&As[kk][ty * 4];
      float4 b = *(const float4*)&Bs[kk][tx * 4];
      float av4[4] = {a.x, a.y, a.z, a.w};
      float bv4[4] = {b.x, b.y, b.z, b.w};
      #pragma unroll
      for (int i = 0; i < 4; i++)
        #pragma unroll
        for (int j = 0; j < 4; j++)
          acc[i][j] += av4[i] * bv4[j];
    }
    __syncthreads();
  }
  float4 bvec = make_float4(0.f, 0.f, 0.f, 0.f);
  if (flags & 1) bvec = *(const float4*)(bias + c0 + tx * 4);
  #pragma unroll
  for (int i = 0; i < 4; i++){
    int r = r0 + ty * 4 + i;
    float v0 = acc[i][0] + bvec.x, v1 = acc[i][1] + bvec.y;
    float v2 = acc[i][2] + bvec.z, v3 = acc[i][3] + bvec.w;
    if (flags & 2){ v0 = gelu_f(v0); v1 = gelu_f(v1); v2 = gelu_f(v2); v3 = gelu_f(v3); }
    if (flags & 4){
      float4 rv = *(const float4*)(res + (size_t)r * N + c0 + tx * 4);
      v0 += rv.x; v1 += rv.y; v2 += rv.z; v3 += rv.w;
    }
    *(float4*)(C + (size_t)r * N + c0 + tx * 4) = make_float4(v0, v1, v2, v3);
  }
}

// ---------------- self-attention, flash-style, thread-per-query-row ----------------
// qkv layout per row: [q(256) | k(256) | v(256)]; grid (qtile, head, m)
__global__ __launch_bounds__(256)
void sa_attn_kernel(const float* __restrict__ qkv, float* __restrict__ ob){
  int m = blockIdx.z, h = blockIdx.y;
  int tid = threadIdx.x;
  int row = blockIdx.x * 256 + tid;
  bool valid = row < NCTX;
  __shared__ float Ks[64][32];
  __shared__ float Vs[64][32];
  const float scale = 0.17677669529663687f;  // 1/sqrt(32)
  float4 q[8];
  if (valid){
    const float* qp = qkv + ((size_t)(m * NCTX + row)) * 768 + h * DHEAD;
    #pragma unroll
    for (int i = 0; i < 8; i++){
      q[i] = ((const float4*)qp)[i];
      q[i].x *= scale; q[i].y *= scale; q[i].z *= scale; q[i].w *= scale;
    }
  }
  float mi = -1e30f, li = 0.0f;
  float4 o[8];
  #pragma unroll
  for (int i = 0; i < 8; i++) o[i] = make_float4(0.f, 0.f, 0.f, 0.f);

  for (int kt = 0; kt < NCTX / 64; kt++){
    // cooperative K/V tile load (64 keys x 32 dims, float4 granularity)
    #pragma unroll
    for (int s = 0; s < 2; s++){
      int f = tid + s * 256;           // 0..511
      int key = f >> 3, d4 = (f & 7) * 4;
      const float* rowp = qkv + ((size_t)(m * NCTX + kt * 64 + key)) * 768 + 256 + h * DHEAD + d4;
      *(float4*)&Ks[key][d4] = *(const float4*)rowp;
      *(float4*)&Vs[key][d4] = *(const float4*)(rowp + 256);
    }
    __syncthreads();
    if (valid){
      #pragma unroll
      for (int half = 0; half < 2; half++){
        float sreg[32];
        #pragma unroll
        for (int kk = 0; kk < 32; kk++){
          const float4* kr = (const float4*)&Ks[half * 32 + kk][0];
          float acc = 0.f;
          #pragma unroll
          for (int i = 0; i < 8; i++){
            float4 k4 = kr[i];
            acc += q[i].x * k4.x + q[i].y * k4.y + q[i].z * k4.z + q[i].w * k4.w;
          }
          sreg[kk] = acc;
        }
        float tm = sreg[0];
        #pragma unroll
        for (int kk = 1; kk < 32; kk++) tm = fmaxf(tm, sreg[kk]);
        float mn = fmaxf(mi, tm);
        float corr = __expf(mi - mn);
        li *= corr;
        #pragma unroll
        for (int i = 0; i < 8; i++){
          o[i].x *= corr; o[i].y *= corr; o[i].z *= corr; o[i].w *= corr;
        }
        #pragma unroll
        for (int kk = 0; kk < 32; kk++){
          float p = __expf(sreg[kk] - mn);
          li += p;
          const float4* vr = (const float4*)&Vs[half * 32 + kk][0];
          #pragma unroll
          for (int i = 0; i < 8; i++){
            float4 vv = vr[i];
            o[i].x += p * vv.x; o[i].y += p * vv.y; o[i].z += p * vv.z; o[i].w += p * vv.w;
          }
        }
        mi = mn;
      }
    }
    __syncthreads();
  }
  if (valid){
    float inv = 1.0f / li;
    float* op = ob + ((size_t)(m * NCTX + row)) * DMODEL + h * DHEAD;
    #pragma unroll
    for (int i = 0; i < 8; i++){
      float4 r = o[i];
      r.x *= inv; r.y *= inv; r.z *= inv; r.w *= inv;
      ((float4*)op)[i] = r;
    }
  }
}

// ---------------- cross-attention over 9 gathered neighbours ----------------
// one block per (m,t); tid = h*32 + d; kv_grid row: [k(256) | v(256)]
__global__ __launch_bounds__(256)
void ca_attn_kernel(const float* __restrict__ qb, const float* __restrict__ kv,
                    const int* __restrict__ idx, const float* __restrict__ mask,
                    float* __restrict__ ob){
  int g = blockIdx.x;          // m*NTGT + t
  int m = g >> 11;
  int tid = threadIdx.x;
  const float scale = 0.17677669529663687f;
  float q = qb[(size_t)g * DMODEL + tid] * scale;
  float s[KNB];
  int rws[KNB];
  #pragma unroll
  for (int k = 0; k < KNB; k++){
    int row = idx[(size_t)g * KNB + k];
    rws[k] = row;
    float p = q * kv[((size_t)(m * NCTX + row)) * 512 + tid];
    #pragma unroll
    for (int off = 16; off > 0; off >>= 1) p += __shfl_xor(p, off, 32);
    s[k] = (mask[(size_t)g * KNB + k] > 0.5f) ? p : -1e30f;
  }
  float sm = s[0];
  #pragma unroll
  for (int k = 1; k < KNB; k++) sm = fmaxf(sm, s[k]);
  float den = 0.f, w[KNB];
  #pragma unroll
  for (int k = 0; k < KNB; k++){ w[k] = __expf(s[k] - sm); den += w[k]; }
  float inv = 1.0f / den;
  float o = 0.f;
  #pragma unroll
  for (int k = 0; k < KNB; k++)
    o += w[k] * kv[((size_t)(m * NCTX + rws[k])) * 512 + 256 + tid];
  ob[(size_t)g * DMODEL + tid] = o * inv;
}

// ---------------- host launcher ----------------
extern "C" void kernel_launch(void* const* d_in, const int* in_sizes, int n_in,
                              void* d_out, int out_size, void* d_ws, size_t ws_size,
                              hipStream_t stream){
  const float* xc      = (const float*)d_in[0];
  const float* zc_in   = (const float*)d_in[1];
  const float* xt      = (const float*)d_in[2];
  const float* zt_in   = (const float*)d_in[3];
  const float* sa_wqkv = (const float*)d_in[4];
  const float* sa_wo   = (const float*)d_in[5];
  const float* sa_ln1  = (const float*)d_in[6];
  const float* sa_ln2  = (const float*)d_in[7];
  const float* sa_w1   = (const float*)d_in[8];
  const float* sa_b1   = (const float*)d_in[9];
  const float* sa_w2   = (const float*)d_in[10];
  const float* sa_b2   = (const float*)d_in[11];
  const float* ca_wq   = (const float*)d_in[12];
  const float* ca_wkv  = (const float*)d_in[13];
  const float* ca_wo   = (const float*)d_in[14];
  const float* ca_lnq  = (const float*)d_in[15];
  const float* ca_lnkv = (const float*)d_in[16];
  const float* ca_ln2  = (const float*)d_in[17];
  const float* ca_w1   = (const float*)d_in[18];
  const float* ca_b1   = (const float*)d_in[19];
  const float* ca_w2   = (const float*)d_in[20];
  const float* ca_b2   = (const float*)d_in[21];

  if (ws_size < (size_t)WS_FLOATS * sizeof(float)) return;  // workspace too small
  float* ws    = (float*)d_ws;
  float* zc    = ws + ZC_OFF;
  float* hb    = ws + H_OFF;
  float* qkvb  = ws + QKV_OFF;   // aliased: qkv / kv_grid / ffn-mid
  float* qb    = ws + Q_OFF;
  float* obuf  = ws + O_OFF;
  int*   idxb  = (int*)(ws + IDX_OFF);
  float* maskb = ws + MASK_OFF;
  float* zt    = (float*)d_out;  // zt state lives in d_out

  copy_kernel<<<RC * DMODEL / 4 / 256, 256, 0, stream>>>(zc_in, zc, RC * DMODEL / 4);
  copy_kernel<<<RT * DMODEL / 4 / 256, 256, 0, stream>>>(zt_in, zt, RT * DMODEL / 4);
  nn_idx_kernel<<<(MB * NTGT) / 256, 256, 0, stream>>>(xc, xt, idxb, maskb);

  for (int l = 0; l < LAYERS; l++){
    // ---------- self-attention block on zc ----------
    ln_kernel<<<RC / 4, 256, 0, stream>>>(zc, sa_ln1 + l * 2 * DMODEL, hb, RC);
    gemm_kernel<<<dim3(768 / BN, RC / BM), 256, 0, stream>>>(
        hb, sa_wqkv + (size_t)l * DMODEL * 768, nullptr, nullptr, qkvb, RC, DMODEL, 768, 0);
    sa_attn_kernel<<<dim3((NCTX + 255) / 256, NHEAD, MB), 256, 0, stream>>>(qkvb, obuf);
    gemm_kernel<<<dim3(DMODEL / BN, RC / BM), 256, 0, stream>>>(
        obuf, sa_wo + (size_t)l * DMODEL * DMODEL, nullptr, zc, zc, RC, DMODEL, DMODEL, 4);
    ln_kernel<<<RC / 4, 256, 0, stream>>>(zc, sa_ln2 + l * 2 * DMODEL, hb, RC);
    gemm_kernel<<<dim3(FF / BN, RC / BM), 256, 0, stream>>>(
        hb, sa_w1 + (size_t)l * DMODEL * FF, sa_b1 + l * FF, nullptr, qkvb, RC, DMODEL, FF, 1 | 2);
    gemm_kernel<<<dim3(DMODEL / BN, RC / BM), 256, 0, stream>>>(
        qkvb, sa_w2 + (size_t)l * FF * DMODEL, sa_b2 + l * DMODEL, zc, zc, RC, FF, DMODEL, 1 | 4);

    // ---------- cross-attention block on zt ----------
    // LN+wkv commute with the neighbour gather: compute kv over the 1600 grid rows once.
    ln_kernel<<<RC / 4, 256, 0, stream>>>(zc, ca_lnkv + l * 2 * DMODEL, hb, RC);
    gemm_kernel<<<dim3(512 / BN, RC / BM), 256, 0, stream>>>(
        hb, ca_wkv + (size_t)l * DMODEL * 512, nullptr, nullptr, qkvb, RC, DMODEL, 512, 0);
    ln_kernel<<<RT / 4, 256, 0, stream>>>(zt, ca_lnq + l * 2 * DMODEL, hb, RT);
    gemm_kernel<<<dim3(DMODEL / BN, RT / BM), 256, 0, stream>>>(
        hb, ca_wq + (size_t)l * DMODEL * DMODEL, nullptr, nullptr, qb, RT, DMODEL, DMODEL, 0);
    ca_attn_kernel<<<RT, 256, 0, stream>>>(qb, qkvb, idxb, maskb, obuf);
    gemm_kernel<<<dim3(DMODEL / BN, RT / BM), 256, 0, stream>>>(
        obuf, ca_wo + (size_t)l * DMODEL * DMODEL, nullptr, zt, zt, RT, DMODEL, DMODEL, 4);
    ln_kernel<<<RT / 4, 256, 0, stream>>>(zt, ca_ln2 + l * 2 * DMODEL, hb, RT);
    gemm_kernel<<<dim3(FF / BN, RT / BM), 256, 0, stream>>>(
        hb, ca_w1 + (size_t)l * DMODEL * FF, ca_b1 + l * FF, nullptr, qkvb, RT, DMODEL, FF, 1 | 2);
    gemm_kernel<<<dim3(DMODEL / BN, RT / BM), 256, 0, stream>>>(
        qkvb, ca_w2 + (size_t)l * FF * DMODEL, ca_b2 + l * DMODEL, zt, zt, RT, FF, DMODEL, 1 | 4);
  }
}

// Round 2
// 1562.541 us; speedup vs baseline: 1.0827x; 1.0827x over previous
//
#include <hip/hip_runtime.h>
#include <math.h>

// ---------------- problem constants ----------------
#define LAYERS 2
#define DMODEL 256
#define NHEAD  8
#define DHEAD  32
#define FF     512
#define KNB    9
#define MB     4
#define G1D    40
#define G2D    40
#define NTGT   2048
#define NCTX   1600          // G1D*G2D
#define RC     (MB*NCTX)     // 6400 grid rows
#define RT     (MB*NTGT)     // 8192 target rows

// ---------------- workspace layout (float offsets) ----------------
#define ZC_OFF    0                         // 1,638,400 f  : zc state
#define H_OFF     1638400                   // 2,097,152 f  : LN output (max RT rows)
#define QKV_OFF   (H_OFF + 2097152)         // 4,915,200 f  : qkv / kv_grid / ffn-mid (aliased)
#define Q_OFF     (QKV_OFF + 4915200)       // 2,097,152 f  : CA q
#define O_OFF     (Q_OFF + 2097152)         // 2,097,152 f  : attention out
#define IDX_OFF   (O_OFF + 2097152)         // 73,728 int
#define MASK_OFF  (IDX_OFF + 73728)         // 73,728 f
#define WS_FLOATS (MASK_OFF + 73728)        // 12,992,512 f = ~52 MB

static __device__ __forceinline__ float gelu_f(float x){
  // jax.nn.gelu approximate=True (tanh form)
  float t = tanhf(0.7978845608028654f * (x + 0.044715f * x * x * x));
  return 0.5f * x * (1.0f + t);
}

// ---------------- utility: vectorized copy ----------------
__global__ void copy_kernel(const float* __restrict__ src, float* __restrict__ dst, int n4){
  int i = blockIdx.x * blockDim.x + threadIdx.x;
  if (i < n4) ((float4*)dst)[i] = ((const float4*)src)[i];
}

// ---------------- nearest-grid-neighbour index/mask precompute ----------------
__global__ void nn_idx_kernel(const float* __restrict__ xc, const float* __restrict__ xt,
                              int* __restrict__ idx, float* __restrict__ mask){
  int g = blockIdx.x * blockDim.x + threadIdx.x;  // m*NTGT + t
  if (g >= MB * NTGT) return;
  int m = g >> 11;  // / NTGT
  float x0 = xt[(size_t)g * 2 + 0];
  float x1 = xt[(size_t)g * 2 + 1];
  const float* xcm = xc + (size_t)m * G1D * G2D * 2;
  int n0 = 0; float b0 = 1e30f;
  for (int i = 0; i < G1D; i++){
    float d = fabsf(x0 - xcm[i * (G2D * 2)]);
    if (d < b0){ b0 = d; n0 = i; }
  }
  int n1 = 0; float b1 = 1e30f;
  for (int j = 0; j < G2D; j++){
    float d = fabsf(x1 - xcm[j * 2 + 1]);
    if (d < b1){ b1 = d; n1 = j; }
  }
  #pragma unroll
  for (int a = 0; a < 3; a++){
    int r0 = n0 + a - 1;
    bool v0 = (r0 >= 0) && (r0 < G1D);
    int i0 = min(max(r0, 0), G1D - 1);
    #pragma unroll
    for (int b = 0; b < 3; b++){
      int r1 = n1 + b - 1;
      bool v1 = (r1 >= 0) && (r1 < G2D);
      int i1 = min(max(r1, 0), G2D - 1);
      idx [(size_t)g * KNB + a * 3 + b] = i0 * G2D + i1;
      mask[(size_t)g * KNB + a * 3 + b] = (v0 && v1) ? 1.0f : 0.0f;
    }
  }
}

// ---------------- LayerNorm: one wave per 256-wide row ----------------
__global__ __launch_bounds__(256)
void ln_kernel(const float* __restrict__ x, const float* __restrict__ gb,
               float* __restrict__ y, int rows){
  int gw   = blockIdx.x * 4 + (threadIdx.x >> 6);
  int lane = threadIdx.x & 63;
  if (gw >= rows) return;
  const float* xr = x + (size_t)gw * DMODEL;
  int d0 = lane * 4;
  float4 xv = *(const float4*)(xr + d0);
  float s = xv.x + xv.y + xv.z + xv.w;
  #pragma unroll
  for (int off = 32; off > 0; off >>= 1) s += __shfl_xor(s, off);
  float mu = s * (1.0f / DMODEL);
  float dx0 = xv.x - mu, dx1 = xv.y - mu, dx2 = xv.z - mu, dx3 = xv.w - mu;
  float v = dx0*dx0 + dx1*dx1 + dx2*dx2 + dx3*dx3;
  #pragma unroll
  for (int off = 32; off > 0; off >>= 1) v += __shfl_xor(v, off);
  float rs = rsqrtf(v * (1.0f / DMODEL) + 1e-5f);
  float4 g = *(const float4*)(gb + d0);
  float4 b = *(const float4*)(gb + DMODEL + d0);
  float4 o;
  o.x = dx0 * rs * g.x + b.x;
  o.y = dx1 * rs * g.y + b.y;
  o.z = dx2 * rs * g.z + b.z;
  o.w = dx3 * rs * g.w + b.w;
  *(float4*)(y + (size_t)gw * DMODEL + d0) = o;
}

// ---------------- tiled fp32 GEMM: C[R,N] = A[R,K] @ W[K,N] (+bias)(+gelu)(+res) ----------------
#define BM 64
#define BN 64
#define BK 16
__global__ __launch_bounds__(256)
void gemm_kernel(const float* __restrict__ A, const float* __restrict__ W,
                 const float* __restrict__ bias, const float* __restrict__ res,
                 float* __restrict__ C, int R, int K, int N, int flags){
  __shared__ float As[BK][BM + 4];
  __shared__ float Bs[BK][BN + 4];
  int tid = threadIdx.x;
  int tx = tid & 15, ty = tid >> 4;
  int r0 = blockIdx.y * BM, c0 = blockIdx.x * BN;
  int arow = tid >> 2, ak = (tid & 3) * 4;
  int bkk  = tid >> 4, bcol = (tid & 15) * 4;
  float acc[4][4] = {};
  for (int k0 = 0; k0 < K; k0 += BK){
    float4 av = *(const float4*)(A + (size_t)(r0 + arow) * K + k0 + ak);
    As[ak + 0][arow] = av.x; As[ak + 1][arow] = av.y;
    As[ak + 2][arow] = av.z; As[ak + 3][arow] = av.w;
    float4 bv = *(const float4*)(W + (size_t)(k0 + bkk) * N + c0 + bcol);
    *(float4*)&Bs[bkk][bcol] = bv;
    __syncthreads();
    #pragma unroll
    for (int kk = 0; kk < BK; kk++){
      float4 a = *(const float4*)&As[kk][ty * 4];
      float4 b = *(const float4*)&Bs[kk][tx * 4];
      float av4[4] = {a.x, a.y, a.z, a.w};
      float bv4[4] = {b.x, b.y, b.z, b.w};
      #pragma unroll
      for (int i = 0; i < 4; i++)
        #pragma unroll
        for (int j = 0; j < 4; j++)
          acc[i][j] += av4[i] * bv4[j];
    }
    __syncthreads();
  }
  float4 bvec = make_float4(0.f, 0.f, 0.f, 0.f);
  if (flags & 1) bvec = *(const float4*)(bias + c0 + tx * 4);
  #pragma unroll
  for (int i = 0; i < 4; i++){
    int r = r0 + ty * 4 + i;
    float v0 = acc[i][0] + bvec.x, v1 = acc[i][1] + bvec.y;
    float v2 = acc[i][2] + bvec.z, v3 = acc[i][3] + bvec.w;
    if (flags & 2){ v0 = gelu_f(v0); v1 = gelu_f(v1); v2 = gelu_f(v2); v3 = gelu_f(v3); }
    if (flags & 4){
      float4 rv = *(const float4*)(res + (size_t)r * N + c0 + tx * 4);
      v0 += rv.x; v1 += rv.y; v2 += rv.z; v3 += rv.w;
    }
    *(float4*)(C + (size_t)r * N + c0 + tx * 4) = make_float4(v0, v1, v2, v3);
  }
}

// ---------------- self-attention, register-blocked flash ----------------
// Each block: 64 query rows of one (m,h). 256 threads.
// Thread owns 4 rows x 16 dims (half head) x 1/8 of keys.
// lane = g*16 + s*2 + dh : g=row-group(4 rows), s=key-subset(8), dh=dim-half(2)
#define KTILE 64
#define KSTRIDE 36
__global__ __launch_bounds__(256)
void sa_attn_kernel(const float* __restrict__ qkv, float* __restrict__ ob){
  int m = blockIdx.z, h = blockIdx.y;
  int tid  = threadIdx.x;
  int wave = tid >> 6, lane = tid & 63;
  int g  = lane >> 4;
  int s  = (lane >> 1) & 7;
  int dh = lane & 1;
  int rg = wave * 4 + g;                       // row-group 0..15
  int row0 = blockIdx.x * 64 + rg * 4;         // first of 4 rows

  __shared__ float Ks[KTILE][KSTRIDE];
  __shared__ float Vs[KTILE][KSTRIDE];

  const float scale = 0.17677669529663687f;    // 1/sqrt(32)

  // q[4 rows][16 dims] pre-scaled
  float4 q[4][4];
  #pragma unroll
  for (int r = 0; r < 4; r++){
    const float* qp = qkv + ((size_t)(m * NCTX + row0 + r)) * 768 + h * DHEAD + dh * 16;
    #pragma unroll
    for (int d = 0; d < 4; d++){
      float4 v = ((const float4*)qp)[d];
      v.x *= scale; v.y *= scale; v.z *= scale; v.w *= scale;
      q[r][d] = v;
    }
  }

  float mr[4] = {-1e30f, -1e30f, -1e30f, -1e30f};
  float lr[4] = {0.f, 0.f, 0.f, 0.f};
  float4 o[4][4];
  #pragma unroll
  for (int r = 0; r < 4; r++)
    #pragma unroll
    for (int d = 0; d < 4; d++) o[r][d] = make_float4(0.f, 0.f, 0.f, 0.f);

  for (int kt = 0; kt < NCTX / KTILE; kt++){
    // cooperative K/V tile load: 512 float4 each, 2 per thread
    #pragma unroll
    for (int j = 0; j < 2; j++){
      int idx4 = tid * 2 + j;                 // 0..511
      int key = idx4 >> 3, d4 = (idx4 & 7) * 4;
      const float* rowp = qkv + ((size_t)(m * NCTX + kt * KTILE + key)) * 768 + 256 + h * DHEAD + d4;
      *(float4*)&Ks[key][d4] = *(const float4*)rowp;
      *(float4*)&Vs[key][d4] = *(const float4*)(rowp + 256);
    }
    __syncthreads();

    // scores: 8 keys (key = i*8+s) x 4 rows, 16-dim partial then dim-half combine
    float sc[4][8];
    #pragma unroll
    for (int i = 0; i < 8; i++){
      int key = i * 8 + s;
      const float4* kr = (const float4*)&Ks[key][dh * 16];
      float4 k0 = kr[0], k1 = kr[1], k2 = kr[2], k3 = kr[3];
      #pragma unroll
      for (int r = 0; r < 4; r++){
        float acc = q[r][0].x*k0.x + q[r][0].y*k0.y + q[r][0].z*k0.z + q[r][0].w*k0.w
                  + q[r][1].x*k1.x + q[r][1].y*k1.y + q[r][1].z*k1.z + q[r][1].w*k1.w
                  + q[r][2].x*k2.x + q[r][2].y*k2.y + q[r][2].z*k2.z + q[r][2].w*k2.w
                  + q[r][3].x*k3.x + q[r][3].y*k3.y + q[r][3].z*k3.z + q[r][3].w*k3.w;
        sc[r][i] = acc;
      }
    }
    #pragma unroll
    for (int r = 0; r < 4; r++)
      #pragma unroll
      for (int i = 0; i < 8; i++)
        sc[r][i] += __shfl_xor(sc[r][i], 1);   // combine dim halves

    // online softmax per thread (its 8 keys)
    #pragma unroll
    for (int r = 0; r < 4; r++){
      float tm = sc[r][0];
      #pragma unroll
      for (int i = 1; i < 8; i++) tm = fmaxf(tm, sc[r][i]);
      float mn = fmaxf(mr[r], tm);
      float corr = __expf(mr[r] - mn);
      lr[r] *= corr;
      #pragma unroll
      for (int d = 0; d < 4; d++){
        o[r][d].x *= corr; o[r][d].y *= corr; o[r][d].z *= corr; o[r][d].w *= corr;
      }
      #pragma unroll
      for (int i = 0; i < 8; i++){
        float p = __expf(sc[r][i] - mn);
        lr[r] += p;
        sc[r][i] = p;
      }
      mr[r] = mn;
    }

    // PV accumulate
    #pragma unroll
    for (int i = 0; i < 8; i++){
      int key = i * 8 + s;
      const float4* vr = (const float4*)&Vs[key][dh * 16];
      float4 v0 = vr[0], v1 = vr[1], v2 = vr[2], v3 = vr[3];
      #pragma unroll
      for (int r = 0; r < 4; r++){
        float p = sc[r][i];
        o[r][0].x += p*v0.x; o[r][0].y += p*v0.y; o[r][0].z += p*v0.z; o[r][0].w += p*v0.w;
        o[r][1].x += p*v1.x; o[r][1].y += p*v1.y; o[r][1].z += p*v1.z; o[r][1].w += p*v1.w;
        o[r][2].x += p*v2.x; o[r][2].y += p*v2.y; o[r][2].z += p*v2.z; o[r][2].w += p*v2.w;
        o[r][3].x += p*v3.x; o[r][3].y += p*v3.y; o[r][3].z += p*v3.z; o[r][3].w += p*v3.w;
      }
    }
    __syncthreads();
  }

  // merge the 8 key-subset partials (lane bits 1..3)
  #pragma unroll
  for (int step = 2; step <= 8; step <<= 1){
    #pragma unroll
    for (int r = 0; r < 4; r++){
      float mo = __shfl_xor(mr[r], step);
      float lo = __shfl_xor(lr[r], step);
      float mn = fmaxf(mr[r], mo);
      float a = __expf(mr[r] - mn);
      float b = __expf(mo - mn);
      lr[r] = lr[r] * a + lo * b;
      #pragma unroll
      for (int d = 0; d < 4; d++){
        float4 ov = o[r][d];
        float ox = __shfl_xor(ov.x, step);
        float oy = __shfl_xor(ov.y, step);
        float oz = __shfl_xor(ov.z, step);
        float ow = __shfl_xor(ov.w, step);
        o[r][d].x = ov.x * a + ox * b;
        o[r][d].y = ov.y * a + oy * b;
        o[r][d].z = ov.z * a + oz * b;
        o[r][d].w = ov.w * a + ow * b;
      }
      mr[r] = mn;
    }
  }

  // write: s-lanes 0..3 each store float4 #s of every row (static-index predicated)
  if (s < 4){
    #pragma unroll
    for (int r = 0; r < 4; r++){
      float inv = 1.0f / lr[r];
      float* op = ob + ((size_t)(m * NCTX + row0 + r)) * DMODEL + h * DHEAD + dh * 16;
      #pragma unroll
      for (int d = 0; d < 4; d++){
        if (s == d){
          float4 v = o[r][d];
          v.x *= inv; v.y *= inv; v.z *= inv; v.w *= inv;
          *(float4*)(op + d * 4) = v;
        }
      }
    }
  }
}

// ---------------- cross-attention over 9 gathered neighbours ----------------
__global__ __launch_bounds__(256)
void ca_attn_kernel(const float* __restrict__ qb, const float* __restrict__ kv,
                    const int* __restrict__ idx, const float* __restrict__ mask,
                    float* __restrict__ ob){
  int g = blockIdx.x;          // m*NTGT + t
  int m = g >> 11;
  int tid = threadIdx.x;
  const float scale = 0.17677669529663687f;
  float q = qb[(size_t)g * DMODEL + tid] * scale;
  float s[KNB];
  int rws[KNB];
  #pragma unroll
  for (int k = 0; k < KNB; k++){
    int row = idx[(size_t)g * KNB + k];
    rws[k] = row;
    float p = q * kv[((size_t)(m * NCTX + row)) * 512 + tid];
    #pragma unroll
    for (int off = 16; off > 0; off >>= 1) p += __shfl_xor(p, off, 32);
    s[k] = (mask[(size_t)g * KNB + k] > 0.5f) ? p : -1e30f;
  }
  float sm = s[0];
  #pragma unroll
  for (int k = 1; k < KNB; k++) sm = fmaxf(sm, s[k]);
  float den = 0.f, w[KNB];
  #pragma unroll
  for (int k = 0; k < KNB; k++){ w[k] = __expf(s[k] - sm); den += w[k]; }
  float inv = 1.0f / den;
  float o = 0.f;
  #pragma unroll
  for (int k = 0; k < KNB; k++)
    o += w[k] * kv[((size_t)(m * NCTX + rws[k])) * 512 + 256 + tid];
  ob[(size_t)g * DMODEL + tid] = o * inv;
}

// ---------------- host launcher ----------------
extern "C" void kernel_launch(void* const* d_in, const int* in_sizes, int n_in,
                              void* d_out, int out_size, void* d_ws, size_t ws_size,
                              hipStream_t stream){
  const float* xc      = (const float*)d_in[0];
  const float* zc_in   = (const float*)d_in[1];
  const float* xt      = (const float*)d_in[2];
  const float* zt_in   = (const float*)d_in[3];
  const float* sa_wqkv = (const float*)d_in[4];
  const float* sa_wo   = (const float*)d_in[5];
  const float* sa_ln1  = (const float*)d_in[6];
  const float* sa_ln2  = (const float*)d_in[7];
  const float* sa_w1   = (const float*)d_in[8];
  const float* sa_b1   = (const float*)d_in[9];
  const float* sa_w2   = (const float*)d_in[10];
  const float* sa_b2   = (const float*)d_in[11];
  const float* ca_wq   = (const float*)d_in[12];
  const float* ca_wkv  = (const float*)d_in[13];
  const float* ca_wo   = (const float*)d_in[14];
  const float* ca_lnq  = (const float*)d_in[15];
  const float* ca_lnkv = (const float*)d_in[16];
  const float* ca_ln2  = (const float*)d_in[17];
  const float* ca_w1   = (const float*)d_in[18];
  const float* ca_b1   = (const float*)d_in[19];
  const float* ca_w2   = (const float*)d_in[20];
  const float* ca_b2   = (const float*)d_in[21];

  if (ws_size < (size_t)WS_FLOATS * sizeof(float)) return;
  float* ws    = (float*)d_ws;
  float* zc    = ws + ZC_OFF;
  float* hb    = ws + H_OFF;
  float* qkvb  = ws + QKV_OFF;
  float* qb    = ws + Q_OFF;
  float* obuf  = ws + O_OFF;
  int*   idxb  = (int*)(ws + IDX_OFF);
  float* maskb = ws + MASK_OFF;
  float* zt    = (float*)d_out;

  copy_kernel<<<RC * DMODEL / 4 / 256, 256, 0, stream>>>(zc_in, zc, RC * DMODEL / 4);
  copy_kernel<<<RT * DMODEL / 4 / 256, 256, 0, stream>>>(zt_in, zt, RT * DMODEL / 4);
  nn_idx_kernel<<<(MB * NTGT) / 256, 256, 0, stream>>>(xc, xt, idxb, maskb);

  for (int l = 0; l < LAYERS; l++){
    // ---------- self-attention block on zc ----------
    ln_kernel<<<RC / 4, 256, 0, stream>>>(zc, sa_ln1 + l * 2 * DMODEL, hb, RC);
    gemm_kernel<<<dim3(768 / BN, RC / BM), 256, 0, stream>>>(
        hb, sa_wqkv + (size_t)l * DMODEL * 768, nullptr, nullptr, qkvb, RC, DMODEL, 768, 0);
    sa_attn_kernel<<<dim3(NCTX / 64, NHEAD, MB), 256, 0, stream>>>(qkvb, obuf);
    gemm_kernel<<<dim3(DMODEL / BN, RC / BM), 256, 0, stream>>>(
        obuf, sa_wo + (size_t)l * DMODEL * DMODEL, nullptr, zc, zc, RC, DMODEL, DMODEL, 4);
    ln_kernel<<<RC / 4, 256, 0, stream>>>(zc, sa_ln2 + l * 2 * DMODEL, hb, RC);
    gemm_kernel<<<dim3(FF / BN, RC / BM), 256, 0, stream>>>(
        hb, sa_w1 + (size_t)l * DMODEL * FF, sa_b1 + l * FF, nullptr, qkvb, RC, DMODEL, FF, 1 | 2);
    gemm_kernel<<<dim3(DMODEL / BN, RC / BM), 256, 0, stream>>>(
        qkvb, sa_w2 + (size_t)l * FF * DMODEL, sa_b2 + l * DMODEL, zc, zc, RC, FF, DMODEL, 1 | 4);

    // ---------- cross-attention block on zt ----------
    ln_kernel<<<RC / 4, 256, 0, stream>>>(zc, ca_lnkv + l * 2 * DMODEL, hb, RC);
    gemm_kernel<<<dim3(512 / BN, RC / BM), 256, 0, stream>>>(
        hb, ca_wkv + (size_t)l * DMODEL * 512, nullptr, nullptr, qkvb, RC, DMODEL, 512, 0);
    ln_kernel<<<RT / 4, 256, 0, stream>>>(zt, ca_lnq + l * 2 * DMODEL, hb, RT);
    gemm_kernel<<<dim3(DMODEL / BN, RT / BM), 256, 0, stream>>>(
        hb, ca_wq + (size_t)l * DMODEL * DMODEL, nullptr, nullptr, qb, RT, DMODEL, DMODEL, 0);
    ca_attn_kernel<<<RT, 256, 0, stream>>>(qb, qkvb, idxb, maskb, obuf);
    gemm_kernel<<<dim3(DMODEL / BN, RT / BM), 256, 0, stream>>>(
        obuf, ca_wo + (size_t)l * DMODEL * DMODEL, nullptr, zt, zt, RT, DMODEL, DMODEL, 4);
    ln_kernel<<<RT / 4, 256, 0, stream>>>(zt, ca_ln2 + l * 2 * DMODEL, hb, RT);
    gemm_kernel<<<dim3(FF / BN, RT / BM), 256, 0, stream>>>(
        hb, ca_w1 + (size_t)l * DMODEL * FF, ca_b1 + l * FF, nullptr, qkvb, RT, DMODEL, FF, 1 | 2);
    gemm_kernel<<<dim3(DMODEL / BN, RT / BM), 256, 0, stream>>>(
        qkvb, sa_w2 == ca_w2 ? ca_w2 : ca_w2 + (size_t)l * FF * DMODEL, ca_b2 + l * DMODEL, zt, zt, RT, FF, DMODEL, 1 | 4);
  }
}

// Round 3
// 781.644 us; speedup vs baseline: 2.1643x; 1.9990x over previous
//
#include <hip/hip_runtime.h>
#include <math.h>

// ---------------- problem constants ----------------
#define LAYERS 2
#define DMODEL 256
#define NHEAD  8
#define DHEAD  32
#define FF     512
#define KNB    9
#define MB     4
#define G1D    40
#define G2D    40
#define NTGT   2048
#define NCTX   1600          // G1D*G2D
#define RC     (MB*NCTX)     // 6400 grid rows
#define RT     (MB*NTGT)     // 8192 target rows

typedef __attribute__((ext_vector_type(8))) short short8;   // 8 bf16 (4 VGPRs)
typedef __attribute__((ext_vector_type(4))) float f32x4;    // mfma C/D

// ---------------- workspace layout (float offsets) ----------------
#define ZC_OFF    0
#define H_OFF     1638400
#define QKV_OFF   (H_OFF + 2097152)
#define Q_OFF     (QKV_OFF + 4915200)
#define O_OFF     (Q_OFF + 2097152)
#define IDX_OFF   (O_OFF + 2097152)
#define MASK_OFF  (IDX_OFF + 73728)
#define WS_FLOATS (MASK_OFF + 73728)

static __device__ __forceinline__ float gelu_f(float x){
  float t = tanhf(0.7978845608028654f * (x + 0.044715f * x * x * x));
  return 0.5f * x * (1.0f + t);
}

static __device__ __forceinline__ unsigned int bf16_rne(float x){
  unsigned int u = __float_as_uint(x);
  return (u + 0x7fffu + ((u >> 16) & 1u)) >> 16;
}
static __device__ __forceinline__ unsigned int pack_bf16x2(float lo, float hi){
  return bf16_rne(lo) | (bf16_rne(hi) << 16);
}

// ---------------- utility: vectorized copy ----------------
__global__ void copy_kernel(const float* __restrict__ src, float* __restrict__ dst, int n4){
  int i = blockIdx.x * blockDim.x + threadIdx.x;
  if (i < n4) ((float4*)dst)[i] = ((const float4*)src)[i];
}

// ---------------- nearest-grid-neighbour index/mask precompute ----------------
__global__ void nn_idx_kernel(const float* __restrict__ xc, const float* __restrict__ xt,
                              int* __restrict__ idx, float* __restrict__ mask){
  int g = blockIdx.x * blockDim.x + threadIdx.x;
  if (g >= MB * NTGT) return;
  int m = g >> 11;
  float x0 = xt[(size_t)g * 2 + 0];
  float x1 = xt[(size_t)g * 2 + 1];
  const float* xcm = xc + (size_t)m * G1D * G2D * 2;
  int n0 = 0; float b0 = 1e30f;
  for (int i = 0; i < G1D; i++){
    float d = fabsf(x0 - xcm[i * (G2D * 2)]);
    if (d < b0){ b0 = d; n0 = i; }
  }
  int n1 = 0; float b1 = 1e30f;
  for (int j = 0; j < G2D; j++){
    float d = fabsf(x1 - xcm[j * 2 + 1]);
    if (d < b1){ b1 = d; n1 = j; }
  }
  #pragma unroll
  for (int a = 0; a < 3; a++){
    int r0 = n0 + a - 1;
    bool v0 = (r0 >= 0) && (r0 < G1D);
    int i0 = min(max(r0, 0), G1D - 1);
    #pragma unroll
    for (int b = 0; b < 3; b++){
      int r1 = n1 + b - 1;
      bool v1 = (r1 >= 0) && (r1 < G2D);
      int i1 = min(max(r1, 0), G2D - 1);
      idx [(size_t)g * KNB + a * 3 + b] = i0 * G2D + i1;
      mask[(size_t)g * KNB + a * 3 + b] = (v0 && v1) ? 1.0f : 0.0f;
    }
  }
}

// ---------------- LayerNorm: one wave per 256-wide row ----------------
__global__ __launch_bounds__(256)
void ln_kernel(const float* __restrict__ x, const float* __restrict__ gb,
               float* __restrict__ y, int rows){
  int gw   = blockIdx.x * 4 + (threadIdx.x >> 6);
  int lane = threadIdx.x & 63;
  if (gw >= rows) return;
  const float* xr = x + (size_t)gw * DMODEL;
  int d0 = lane * 4;
  float4 xv = *(const float4*)(xr + d0);
  float s = xv.x + xv.y + xv.z + xv.w;
  #pragma unroll
  for (int off = 32; off > 0; off >>= 1) s += __shfl_xor(s, off);
  float mu = s * (1.0f / DMODEL);
  float dx0 = xv.x - mu, dx1 = xv.y - mu, dx2 = xv.z - mu, dx3 = xv.w - mu;
  float v = dx0*dx0 + dx1*dx1 + dx2*dx2 + dx3*dx3;
  #pragma unroll
  for (int off = 32; off > 0; off >>= 1) v += __shfl_xor(v, off);
  float rs = rsqrtf(v * (1.0f / DMODEL) + 1e-5f);
  float4 g = *(const float4*)(gb + d0);
  float4 b = *(const float4*)(gb + DMODEL + d0);
  float4 o;
  o.x = dx0 * rs * g.x + b.x;
  o.y = dx1 * rs * g.y + b.y;
  o.z = dx2 * rs * g.z + b.z;
  o.w = dx3 * rs * g.w + b.w;
  *(float4*)(y + (size_t)gw * DMODEL + d0) = o;
}

// ---------------- tiled fp32 GEMM (+bias)(+gelu)(+res)(+bf16 out) ----------------
// flags: 1=bias, 2=gelu, 4=residual, 8=write bf16 (C reinterpreted as ushort*)
#define BM 64
#define BN 64
#define BK 16
__global__ __launch_bounds__(256)
void gemm_kernel(const float* __restrict__ A, const float* __restrict__ W,
                 const float* __restrict__ bias, const float* __restrict__ res,
                 float* __restrict__ C, int R, int K, int N, int flags){
  __shared__ float As[BK][BM + 4];
  __shared__ float Bs[BK][BN + 4];
  int tid = threadIdx.x;
  int tx = tid & 15, ty = tid >> 4;
  int r0 = blockIdx.y * BM, c0 = blockIdx.x * BN;
  int arow = tid >> 2, ak = (tid & 3) * 4;
  int bkk  = tid >> 4, bcol = (tid & 15) * 4;
  float acc[4][4] = {};
  for (int k0 = 0; k0 < K; k0 += BK){
    float4 av = *(const float4*)(A + (size_t)(r0 + arow) * K + k0 + ak);
    As[ak + 0][arow] = av.x; As[ak + 1][arow] = av.y;
    As[ak + 2][arow] = av.z; As[ak + 3][arow] = av.w;
    float4 bv = *(const float4*)(W + (size_t)(k0 + bkk) * N + c0 + bcol);
    *(float4*)&Bs[bkk][bcol] = bv;
    __syncthreads();
    #pragma unroll
    for (int kk = 0; kk < BK; kk++){
      float4 a = *(const float4*)&As[kk][ty * 4];
      float4 b = *(const float4*)&Bs[kk][tx * 4];
      float av4[4] = {a.x, a.y, a.z, a.w};
      float bv4[4] = {b.x, b.y, b.z, b.w};
      #pragma unroll
      for (int i = 0; i < 4; i++)
        #pragma unroll
        for (int j = 0; j < 4; j++)
          acc[i][j] += av4[i] * bv4[j];
    }
    __syncthreads();
  }
  float4 bvec = make_float4(0.f, 0.f, 0.f, 0.f);
  if (flags & 1) bvec = *(const float4*)(bias + c0 + tx * 4);
  #pragma unroll
  for (int i = 0; i < 4; i++){
    int r = r0 + ty * 4 + i;
    float v0 = acc[i][0] + bvec.x, v1 = acc[i][1] + bvec.y;
    float v2 = acc[i][2] + bvec.z, v3 = acc[i][3] + bvec.w;
    if (flags & 2){ v0 = gelu_f(v0); v1 = gelu_f(v1); v2 = gelu_f(v2); v3 = gelu_f(v3); }
    if (flags & 4){
      float4 rv = *(const float4*)(res + (size_t)r * N + c0 + tx * 4);
      v0 += rv.x; v1 += rv.y; v2 += rv.z; v3 += rv.w;
    }
    if (flags & 8){
      unsigned short* Cb = (unsigned short*)C;
      uint2 w;
      w.x = pack_bf16x2(v0, v1);
      w.y = pack_bf16x2(v2, v3);
      *(uint2*)(Cb + (size_t)r * N + c0 + tx * 4) = w;
    } else {
      *(float4*)(C + (size_t)r * N + c0 + tx * 4) = make_float4(v0, v1, v2, v3);
    }
  }
}

// ---------------- self-attention: bf16 MFMA flash (swapped-operand layout) ----------
// grid (25, NHEAD, MB), block 256 = 4 waves; wave owns 16 q rows.
// S^T = mfma(K_frag, Q_frag): D col=lane&15=q, row=(lane>>4)*4+r=key  [m89 layout]
// O^T = mfma(Vt_frag, P_frag): D col=q, row=dim -> stats & output stay q-aligned.
#define KSTR 40   // shorts per K LDS row (32 data + 8 pad) -> uniform banks for frag reads
#define VSTR 72   // shorts per Vt LDS row (64 data + 8 pad)
#define PSTR 72   // shorts per P LDS row  (64 data + 8 pad)
__global__ __launch_bounds__(256)
void sa_attn_mfma(const unsigned short* __restrict__ qkv, float* __restrict__ ob){
  int m = blockIdx.z, h = blockIdx.y;
  int tid  = threadIdx.x;
  int wave = tid >> 6, lane = tid & 63;
  int qr = lane & 15, grp = lane >> 4;
  int q0 = blockIdx.x * 64 + wave * 16;

  __shared__ unsigned short Kls[2][64 * KSTR];
  __shared__ unsigned short Vls[2][32 * VSTR];
  __shared__ unsigned short Pls[4][16 * PSTR];
  unsigned short* Pw = Pls[wave];

  const float scale = 0.17677669529663687f;   // 1/sqrt(32)

  // Q B-frag: lane holds q=lane&15, dh=grp*8..grp*8+7 (constant over kv tiles)
  short8 qf = *(const short8*)(qkv + ((size_t)(m * NCTX + q0 + qr)) * 768 + h * 32 + grp * 8);

  // staging: thread -> (key = tid>>2, dims scol..scol+7)
  int skey = tid >> 2;
  int scol = (tid & 3) * 8;
  const unsigned short* kbase = qkv + (size_t)m * NCTX * 768 + 256 + h * 32 + scol;

  // prologue: tile 0 -> regs
  uint4 kreg = *(const uint4*)(kbase + (size_t)skey * 768);
  uint4 vreg = *(const uint4*)(kbase + (size_t)skey * 768 + 256);

  float mq = -1e30f, lq = 0.0f;
  f32x4 acc0 = {0.f, 0.f, 0.f, 0.f};
  f32x4 acc1 = {0.f, 0.f, 0.f, 0.f};

  // write tile 0 into buffer 0
  {
    *(uint4*)&Kls[0][skey * KSTR + scol] = kreg;
    unsigned int vv[4] = {vreg.x, vreg.y, vreg.z, vreg.w};
    #pragma unroll
    for (int j = 0; j < 4; j++){
      Vls[0][(scol + 2 * j    ) * VSTR + skey] = (unsigned short)(vv[j] & 0xffffu);
      Vls[0][(scol + 2 * j + 1) * VSTR + skey] = (unsigned short)(vv[j] >> 16);
    }
  }

  for (int kt = 0; kt < NCTX / 64; kt++){
    int b = kt & 1;
    __syncthreads();
    if (kt + 1 < NCTX / 64){
      kreg = *(const uint4*)(kbase + (size_t)((kt + 1) * 64 + skey) * 768);
      vreg = *(const uint4*)(kbase + (size_t)((kt + 1) * 64 + skey) * 768 + 256);
    }

    // ---- QK^T (swapped): 4 key-blocks of 16 ----
    f32x4 s0 = {0.f,0.f,0.f,0.f}, s1 = {0.f,0.f,0.f,0.f};
    f32x4 s2 = {0.f,0.f,0.f,0.f}, s3 = {0.f,0.f,0.f,0.f};
    {
      const short8 k0 = *(const short8*)&Kls[b][( 0 + qr) * KSTR + grp * 8];
      const short8 k1 = *(const short8*)&Kls[b][(16 + qr) * KSTR + grp * 8];
      const short8 k2 = *(const short8*)&Kls[b][(32 + qr) * KSTR + grp * 8];
      const short8 k3 = *(const short8*)&Kls[b][(48 + qr) * KSTR + grp * 8];
      s0 = __builtin_amdgcn_mfma_f32_16x16x32_bf16(k0, qf, s0, 0, 0, 0);
      s1 = __builtin_amdgcn_mfma_f32_16x16x32_bf16(k1, qf, s1, 0, 0, 0);
      s2 = __builtin_amdgcn_mfma_f32_16x16x32_bf16(k2, qf, s2, 0, 0, 0);
      s3 = __builtin_amdgcn_mfma_f32_16x16x32_bf16(k3, qf, s3, 0, 0, 0);
    }

    // ---- online softmax (per lane: q = lane&15; keys grp*4+r per block) ----
    float sc[4][4];
    #pragma unroll
    for (int r = 0; r < 4; r++){
      sc[0][r] = s0[r] * scale; sc[1][r] = s1[r] * scale;
      sc[2][r] = s2[r] * scale; sc[3][r] = s3[r] * scale;
    }
    float tm = sc[0][0];
    #pragma unroll
    for (int kb = 0; kb < 4; kb++)
      #pragma unroll
      for (int r = 0; r < 4; r++) tm = fmaxf(tm, sc[kb][r]);
    tm = fmaxf(tm, __shfl_xor(tm, 16));
    tm = fmaxf(tm, __shfl_xor(tm, 32));
    float mn = fmaxf(mq, tm);
    float corr = __expf(mq - mn);
    float ts = 0.f;
    float p[4][4];
    #pragma unroll
    for (int kb = 0; kb < 4; kb++)
      #pragma unroll
      for (int r = 0; r < 4; r++){
        float pv = __expf(sc[kb][r] - mn);
        p[kb][r] = pv; ts += pv;
      }
    ts += __shfl_xor(ts, 16);
    ts += __shfl_xor(ts, 32);
    lq = lq * corr + ts;
    mq = mn;
    #pragma unroll
    for (int r = 0; r < 4; r++){ acc0[r] *= corr; acc1[r] *= corr; }

    // ---- P -> LDS (bf16, per-wave buffer; key = kb*16 + grp*4 + r) ----
    #pragma unroll
    for (int kb = 0; kb < 4; kb++){
      *(unsigned int*)&Pw[qr * PSTR + kb * 16 + grp * 4]     = pack_bf16x2(p[kb][0], p[kb][1]);
      *(unsigned int*)&Pw[qr * PSTR + kb * 16 + grp * 4 + 2] = pack_bf16x2(p[kb][2], p[kb][3]);
    }

    // ---- PV (swapped): O^T += V^T . P^T, two key-halves x two dim-blocks ----
    #pragma unroll
    for (int hh = 0; hh < 2; hh++){
      const short8 pf = *(const short8*)&Pw[qr * PSTR + hh * 32 + grp * 8];
      const short8 v0 = *(const short8*)&Vls[b][( 0 + qr) * VSTR + hh * 32 + grp * 8];
      const short8 v1 = *(const short8*)&Vls[b][(16 + qr) * VSTR + hh * 32 + grp * 8];
      acc0 = __builtin_amdgcn_mfma_f32_16x16x32_bf16(v0, pf, acc0, 0, 0, 0);
      acc1 = __builtin_amdgcn_mfma_f32_16x16x32_bf16(v1, pf, acc1, 0, 0, 0);
    }

    // ---- stage tile kt+1 into other buffer ----
    if (kt + 1 < NCTX / 64){
      *(uint4*)&Kls[b ^ 1][skey * KSTR + scol] = kreg;
      unsigned int vv[4] = {vreg.x, vreg.y, vreg.z, vreg.w};
      #pragma unroll
      for (int j = 0; j < 4; j++){
        Vls[b ^ 1][(scol + 2 * j    ) * VSTR + skey] = (unsigned short)(vv[j] & 0xffffu);
        Vls[b ^ 1][(scol + 2 * j + 1) * VSTR + skey] = (unsigned short)(vv[j] >> 16);
      }
    }
  }

  // ---- epilogue: O = O^T / l, write float4 per dim-block ----
  float inv = 1.0f / lq;
  float* op = ob + ((size_t)(m * NCTX + q0 + qr)) * DMODEL + h * DHEAD;
  float4 w0, w1;
  w0.x = acc0[0] * inv; w0.y = acc0[1] * inv; w0.z = acc0[2] * inv; w0.w = acc0[3] * inv;
  w1.x = acc1[0] * inv; w1.y = acc1[1] * inv; w1.z = acc1[2] * inv; w1.w = acc1[3] * inv;
  *(float4*)(op + grp * 4)      = w0;   // dims  0..15 : dim = grp*4 + r
  *(float4*)(op + 16 + grp * 4) = w1;   // dims 16..31
}

// ---------------- cross-attention over 9 gathered neighbours ----------------
__global__ __launch_bounds__(256)
void ca_attn_kernel(const float* __restrict__ qb, const float* __restrict__ kv,
                    const int* __restrict__ idx, const float* __restrict__ mask,
                    float* __restrict__ ob){
  int g = blockIdx.x;
  int m = g >> 11;
  int tid = threadIdx.x;
  const float scale = 0.17677669529663687f;
  float q = qb[(size_t)g * DMODEL + tid] * scale;
  float s[KNB];
  int rws[KNB];
  #pragma unroll
  for (int k = 0; k < KNB; k++){
    int row = idx[(size_t)g * KNB + k];
    rws[k] = row;
    float p = q * kv[((size_t)(m * NCTX + row)) * 512 + tid];
    #pragma unroll
    for (int off = 16; off > 0; off >>= 1) p += __shfl_xor(p, off, 32);
    s[k] = (mask[(size_t)g * KNB + k] > 0.5f) ? p : -1e30f;
  }
  float sm = s[0];
  #pragma unroll
  for (int k = 1; k < KNB; k++) sm = fmaxf(sm, s[k]);
  float den = 0.f, w[KNB];
  #pragma unroll
  for (int k = 0; k < KNB; k++){ w[k] = __expf(s[k] - sm); den += w[k]; }
  float inv = 1.0f / den;
  float o = 0.f;
  #pragma unroll
  for (int k = 0; k < KNB; k++)
    o += w[k] * kv[((size_t)(m * NCTX + rws[k])) * 512 + 256 + tid];
  ob[(size_t)g * DMODEL + tid] = o * inv;
}

// ---------------- host launcher ----------------
extern "C" void kernel_launch(void* const* d_in, const int* in_sizes, int n_in,
                              void* d_out, int out_size, void* d_ws, size_t ws_size,
                              hipStream_t stream){
  const float* xc      = (const float*)d_in[0];
  const float* zc_in   = (const float*)d_in[1];
  const float* xt      = (const float*)d_in[2];
  const float* zt_in   = (const float*)d_in[3];
  const float* sa_wqkv = (const float*)d_in[4];
  const float* sa_wo   = (const float*)d_in[5];
  const float* sa_ln1  = (const float*)d_in[6];
  const float* sa_ln2  = (const float*)d_in[7];
  const float* sa_w1   = (const float*)d_in[8];
  const float* sa_b1   = (const float*)d_in[9];
  const float* sa_w2   = (const float*)d_in[10];
  const float* sa_b2   = (const float*)d_in[11];
  const float* ca_wq   = (const float*)d_in[12];
  const float* ca_wkv  = (const float*)d_in[13];
  const float* ca_wo   = (const float*)d_in[14];
  const float* ca_lnq  = (const float*)d_in[15];
  const float* ca_lnkv = (const float*)d_in[16];
  const float* ca_ln2  = (const float*)d_in[17];
  const float* ca_w1   = (const float*)d_in[18];
  const float* ca_b1   = (const float*)d_in[19];
  const float* ca_w2   = (const float*)d_in[20];
  const float* ca_b2   = (const float*)d_in[21];

  if (ws_size < (size_t)WS_FLOATS * sizeof(float)) return;
  float* ws    = (float*)d_ws;
  float* zc    = ws + ZC_OFF;
  float* hb    = ws + H_OFF;
  float* qkvb  = ws + QKV_OFF;   // aliased: bf16 qkv / CA kv (fp32) / ffn-mid (fp32)
  float* qb    = ws + Q_OFF;
  float* obuf  = ws + O_OFF;
  int*   idxb  = (int*)(ws + IDX_OFF);
  float* maskb = ws + MASK_OFF;
  float* zt    = (float*)d_out;

  copy_kernel<<<RC * DMODEL / 4 / 256, 256, 0, stream>>>(zc_in, zc, RC * DMODEL / 4);
  copy_kernel<<<RT * DMODEL / 4 / 256, 256, 0, stream>>>(zt_in, zt, RT * DMODEL / 4);
  nn_idx_kernel<<<(MB * NTGT) / 256, 256, 0, stream>>>(xc, xt, idxb, maskb);

  for (int l = 0; l < LAYERS; l++){
    // ---------- self-attention block on zc ----------
    ln_kernel<<<RC / 4, 256, 0, stream>>>(zc, sa_ln1 + l * 2 * DMODEL, hb, RC);
    gemm_kernel<<<dim3(768 / BN, RC / BM), 256, 0, stream>>>(
        hb, sa_wqkv + (size_t)l * DMODEL * 768, nullptr, nullptr, qkvb, RC, DMODEL, 768, 8);
    sa_attn_mfma<<<dim3(NCTX / 64, NHEAD, MB), 256, 0, stream>>>(
        (const unsigned short*)qkvb, obuf);
    gemm_kernel<<<dim3(DMODEL / BN, RC / BM), 256, 0, stream>>>(
        obuf, sa_wo + (size_t)l * DMODEL * DMODEL, nullptr, zc, zc, RC, DMODEL, DMODEL, 4);
    ln_kernel<<<RC / 4, 256, 0, stream>>>(zc, sa_ln2 + l * 2 * DMODEL, hb, RC);
    gemm_kernel<<<dim3(FF / BN, RC / BM), 256, 0, stream>>>(
        hb, sa_w1 + (size_t)l * DMODEL * FF, sa_b1 + l * FF, nullptr, qkvb, RC, DMODEL, FF, 1 | 2);
    gemm_kernel<<<dim3(DMODEL / BN, RC / BM), 256, 0, stream>>>(
        qkvb, sa_w2 + (size_t)l * FF * DMODEL, sa_b2 + l * DMODEL, zc, zc, RC, FF, DMODEL, 1 | 4);

    // ---------- cross-attention block on zt ----------
    ln_kernel<<<RC / 4, 256, 0, stream>>>(zc, ca_lnkv + l * 2 * DMODEL, hb, RC);
    gemm_kernel<<<dim3(512 / BN, RC / BM), 256, 0, stream>>>(
        hb, ca_wkv + (size_t)l * DMODEL * 512, nullptr, nullptr, qkvb, RC, DMODEL, 512, 0);
    ln_kernel<<<RT / 4, 256, 0, stream>>>(zt, ca_lnq + l * 2 * DMODEL, hb, RT);
    gemm_kernel<<<dim3(DMODEL / BN, RT / BM), 256, 0, stream>>>(
        hb, ca_wq + (size_t)l * DMODEL * DMODEL, nullptr, nullptr, qb, RT, DMODEL, DMODEL, 0);
    ca_attn_kernel<<<RT, 256, 0, stream>>>(qb, qkvb, idxb, maskb, obuf);
    gemm_kernel<<<dim3(DMODEL / BN, RT / BM), 256, 0, stream>>>(
        obuf, ca_wo + (size_t)l * DMODEL * DMODEL, nullptr, zt, zt, RT, DMODEL, DMODEL, 4);
    ln_kernel<<<RT / 4, 256, 0, stream>>>(zt, ca_ln2 + l * 2 * DMODEL, hb, RT);
    gemm_kernel<<<dim3(FF / BN, RT / BM), 256, 0, stream>>>(
        hb, ca_w1 + (size_t)l * DMODEL * FF, ca_b1 + l * FF, nullptr, qkvb, RT, DMODEL, FF, 1 | 2);
    gemm_kernel<<<dim3(DMODEL / BN, RT / BM), 256, 0, stream>>>(
        qkvb, ca_w2 + (size_t)l * FF * DMODEL, ca_b2 + l * DMODEL, zt, zt, RT, FF, DMODEL, 1 | 4);
  }
}

// Round 4
// 486.151 us; speedup vs baseline: 3.4799x; 1.6078x over previous
//
#include <hip/hip_runtime.h>
#include <math.h>

// ---------------- problem constants ----------------
#define LAYERS 2
#define DMODEL 256
#define NHEAD  8
#define DHEAD  32
#define FF     512
#define KNB    9
#define MB     4
#define G1D    40
#define G2D    40
#define NTGT   2048
#define NCTX   1600          // G1D*G2D
#define RC     (MB*NCTX)     // 6400 grid rows
#define RT     (MB*NTGT)     // 8192 target rows

typedef __attribute__((ext_vector_type(8))) short short8;   // 8 bf16 (4 VGPRs)
typedef __attribute__((ext_vector_type(4))) float f32x4;    // mfma C/D

// ---------------- workspace layout (float offsets) ----------------
#define ZC_OFF    0
#define H_OFF     1638400
#define QKV_OFF   (H_OFF + 2097152)
#define Q_OFF     (QKV_OFF + 4915200)
#define O_OFF     (Q_OFF + 2097152)
#define IDX_OFF   (O_OFF + 2097152)
#define MASK_OFF  (IDX_OFF + 73728)
#define WS_FLOATS (MASK_OFF + 73728)

static __device__ __forceinline__ float gelu_f(float x){
  float t = tanhf(0.7978845608028654f * (x + 0.044715f * x * x * x));
  return 0.5f * x * (1.0f + t);
}

static __device__ __forceinline__ unsigned int bf16_rne(float x){
  unsigned int u = __float_as_uint(x);
  return (u + 0x7fffu + ((u >> 16) & 1u)) >> 16;
}
static __device__ __forceinline__ unsigned int pack_bf16x2(float lo, float hi){
  return bf16_rne(lo) | (bf16_rne(hi) << 16);
}

// ---------------- utility: vectorized copy ----------------
__global__ void copy_kernel(const float* __restrict__ src, float* __restrict__ dst, int n4){
  int i = blockIdx.x * blockDim.x + threadIdx.x;
  if (i < n4) ((float4*)dst)[i] = ((const float4*)src)[i];
}

// ---------------- nearest-grid-neighbour index/mask precompute ----------------
__global__ void nn_idx_kernel(const float* __restrict__ xc, const float* __restrict__ xt,
                              int* __restrict__ idx, float* __restrict__ mask){
  int g = blockIdx.x * blockDim.x + threadIdx.x;
  if (g >= MB * NTGT) return;
  int m = g >> 11;
  float x0 = xt[(size_t)g * 2 + 0];
  float x1 = xt[(size_t)g * 2 + 1];
  const float* xcm = xc + (size_t)m * G1D * G2D * 2;
  int n0 = 0; float b0 = 1e30f;
  for (int i = 0; i < G1D; i++){
    float d = fabsf(x0 - xcm[i * (G2D * 2)]);
    if (d < b0){ b0 = d; n0 = i; }
  }
  int n1 = 0; float b1 = 1e30f;
  for (int j = 0; j < G2D; j++){
    float d = fabsf(x1 - xcm[j * 2 + 1]);
    if (d < b1){ b1 = d; n1 = j; }
  }
  #pragma unroll
  for (int a = 0; a < 3; a++){
    int r0 = n0 + a - 1;
    bool v0 = (r0 >= 0) && (r0 < G1D);
    int i0 = min(max(r0, 0), G1D - 1);
    #pragma unroll
    for (int b = 0; b < 3; b++){
      int r1 = n1 + b - 1;
      bool v1 = (r1 >= 0) && (r1 < G2D);
      int i1 = min(max(r1, 0), G2D - 1);
      idx [(size_t)g * KNB + a * 3 + b] = i0 * G2D + i1;
      mask[(size_t)g * KNB + a * 3 + b] = (v0 && v1) ? 1.0f : 0.0f;
    }
  }
}

// ---------------- LayerNorm: one wave per 256-wide row, bf16 output ----------------
__global__ __launch_bounds__(256)
void ln_kernel(const float* __restrict__ x, const float* __restrict__ gb,
               unsigned short* __restrict__ y, int rows){
  int gw   = blockIdx.x * 4 + (threadIdx.x >> 6);
  int lane = threadIdx.x & 63;
  if (gw >= rows) return;
  const float* xr = x + (size_t)gw * DMODEL;
  int d0 = lane * 4;
  float4 xv = *(const float4*)(xr + d0);
  float s = xv.x + xv.y + xv.z + xv.w;
  #pragma unroll
  for (int off = 32; off > 0; off >>= 1) s += __shfl_xor(s, off);
  float mu = s * (1.0f / DMODEL);
  float dx0 = xv.x - mu, dx1 = xv.y - mu, dx2 = xv.z - mu, dx3 = xv.w - mu;
  float v = dx0*dx0 + dx1*dx1 + dx2*dx2 + dx3*dx3;
  #pragma unroll
  for (int off = 32; off > 0; off >>= 1) v += __shfl_xor(v, off);
  float rs = rsqrtf(v * (1.0f / DMODEL) + 1e-5f);
  float4 g = *(const float4*)(gb + d0);
  float4 b = *(const float4*)(gb + DMODEL + d0);
  uint2 w;
  w.x = pack_bf16x2(dx0 * rs * g.x + b.x, dx1 * rs * g.y + b.y);
  w.y = pack_bf16x2(dx2 * rs * g.z + b.z, dx3 * rs * g.w + b.w);
  *(uint2*)(y + (size_t)gw * DMODEL + d0) = w;
}

// ---------------- bf16 MFMA GEMM: C[R,N] = A[R,K](bf16) @ W[K,N](fp32->bf16) ----------
// flags: 1=bias, 2=gelu, 4=residual(fp32), 8=bf16 out
// Tile 128x64x32; 4 waves, each 64x32 (4x2 frags of 16x16x32).
// LDS: A [128][40] shorts, B^T [64][40] shorts (transposed+converted at stage time).
// Frag reads are b128 with bank spread (20*l16+4*grp)%32 -> uniform 2-way = free.
#define GBM 128
#define GBN 64
#define GBK 32
#define GSTR 40
__global__ __launch_bounds__(256)
void gemm_mfma(const unsigned short* __restrict__ A, const float* __restrict__ W,
               const float* __restrict__ bias, const float* __restrict__ res,
               void* __restrict__ C, int R, int K, int N, int flags){
  __shared__ unsigned short Als[2][GBM * GSTR];
  __shared__ unsigned short Bls[2][GBN * GSTR];
  int tid = threadIdx.x;
  int wave = tid >> 6, lane = tid & 63;
  int wm = wave >> 1, wn = wave & 1;
  int l16 = lane & 15, grp = lane >> 4;
  int r0 = blockIdx.y * GBM, c0 = blockIdx.x * GBN;

  // A staging: elems e=tid, tid+256 ; row=e>>2 (0..127 over 2 halves), kc=(e&3)*8
  int arow = tid >> 2, akc = (tid & 3) * 8;
  // B staging: e=tid, tid+256 ; k=e>>4, n4=(e&15)*4
  int bk = tid >> 4, bn4 = (tid & 15) * 4;

  const unsigned short* Ag = A + (size_t)r0 * K;
  const float* Wg = W + c0;

  int ntiles = K / GBK;

  // prologue: tile 0 -> regs
  uint4 a0 = *(const uint4*)(Ag + (size_t)arow * K + akc);
  uint4 a1 = *(const uint4*)(Ag + (size_t)(arow + 64) * K + akc);
  float4 w0 = *(const float4*)(Wg + (size_t)bk * N + bn4);
  float4 w1 = *(const float4*)(Wg + (size_t)(bk + 16) * N + bn4);

  // write tile 0 into buffer 0
  *(uint4*)&Als[0][arow * GSTR + akc] = a0;
  *(uint4*)&Als[0][(arow + 64) * GSTR + akc] = a1;
  {
    float wv0[4] = {w0.x, w0.y, w0.z, w0.w};
    float wv1[4] = {w1.x, w1.y, w1.z, w1.w};
    #pragma unroll
    for (int j = 0; j < 4; j++){
      Bls[0][(bn4 + j) * GSTR + bk]      = (unsigned short)bf16_rne(wv0[j]);
      Bls[0][(bn4 + j) * GSTR + bk + 16] = (unsigned short)bf16_rne(wv1[j]);
    }
  }

  f32x4 acc[4][2];
  #pragma unroll
  for (int m = 0; m < 4; m++)
    #pragma unroll
    for (int n = 0; n < 2; n++) acc[m][n] = (f32x4){0.f, 0.f, 0.f, 0.f};

  for (int kt = 0; kt < ntiles; kt++){
    int b = kt & 1;
    __syncthreads();
    if (kt + 1 < ntiles){
      int k0 = (kt + 1) * GBK;
      a0 = *(const uint4*)(Ag + (size_t)arow * K + k0 + akc);
      a1 = *(const uint4*)(Ag + (size_t)(arow + 64) * K + k0 + akc);
      w0 = *(const float4*)(Wg + (size_t)(k0 + bk) * N + bn4);
      w1 = *(const float4*)(Wg + (size_t)(k0 + bk + 16) * N + bn4);
    }

    short8 af[4], bf[2];
    #pragma unroll
    for (int m = 0; m < 4; m++)
      af[m] = *(const short8*)&Als[b][(wm * 64 + m * 16 + l16) * GSTR + grp * 8];
    #pragma unroll
    for (int n = 0; n < 2; n++)
      bf[n] = *(const short8*)&Bls[b][(wn * 32 + n * 16 + l16) * GSTR + grp * 8];
    #pragma unroll
    for (int m = 0; m < 4; m++)
      #pragma unroll
      for (int n = 0; n < 2; n++)
        acc[m][n] = __builtin_amdgcn_mfma_f32_16x16x32_bf16(af[m], bf[n], acc[m][n], 0, 0, 0);

    if (kt + 1 < ntiles){
      *(uint4*)&Als[b ^ 1][arow * GSTR + akc] = a0;
      *(uint4*)&Als[b ^ 1][(arow + 64) * GSTR + akc] = a1;
      float wv0[4] = {w0.x, w0.y, w0.z, w0.w};
      float wv1[4] = {w1.x, w1.y, w1.z, w1.w};
      #pragma unroll
      for (int j = 0; j < 4; j++){
        Bls[b ^ 1][(bn4 + j) * GSTR + bk]      = (unsigned short)bf16_rne(wv0[j]);
        Bls[b ^ 1][(bn4 + j) * GSTR + bk + 16] = (unsigned short)bf16_rne(wv1[j]);
      }
    }
  }

  // epilogue: D col = l16 (n), row = grp*4 + reg (within 16-row frag)
  #pragma unroll
  for (int n = 0; n < 2; n++){
    int gc = c0 + wn * 32 + n * 16 + l16;
    float bv = (flags & 1) ? bias[gc] : 0.f;
    #pragma unroll
    for (int m = 0; m < 4; m++){
      int grb = r0 + wm * 64 + m * 16 + grp * 4;
      #pragma unroll
      for (int r = 0; r < 4; r++){
        float v = acc[m][n][r] + bv;
        if (flags & 2) v = gelu_f(v);
        if (flags & 4) v += res[(size_t)(grb + r) * N + gc];
        if (flags & 8) ((unsigned short*)C)[(size_t)(grb + r) * N + gc] = (unsigned short)bf16_rne(v);
        else           ((float*)C)[(size_t)(grb + r) * N + gc] = v;
      }
    }
  }
}

// ---------------- self-attention: bf16 MFMA flash (swapped-operand layout) ----------
#define KSTR 40
#define VSTR 72
#define PSTR 72
__global__ __launch_bounds__(256)
void sa_attn_mfma(const unsigned short* __restrict__ qkv, unsigned short* __restrict__ ob){
  int m = blockIdx.z, h = blockIdx.y;
  int tid  = threadIdx.x;
  int wave = tid >> 6, lane = tid & 63;
  int qr = lane & 15, grp = lane >> 4;
  int q0 = blockIdx.x * 64 + wave * 16;

  __shared__ unsigned short Kls[2][64 * KSTR];
  __shared__ unsigned short Vls[2][32 * VSTR];
  __shared__ unsigned short Pls[4][16 * PSTR];
  unsigned short* Pw = Pls[wave];

  const float scale = 0.17677669529663687f;

  short8 qf = *(const short8*)(qkv + ((size_t)(m * NCTX + q0 + qr)) * 768 + h * 32 + grp * 8);

  int skey = tid >> 2;
  int scol = (tid & 3) * 8;
  const unsigned short* kbase = qkv + (size_t)m * NCTX * 768 + 256 + h * 32 + scol;

  uint4 kreg = *(const uint4*)(kbase + (size_t)skey * 768);
  uint4 vreg = *(const uint4*)(kbase + (size_t)skey * 768 + 256);

  float mq = -1e30f, lq = 0.0f;
  f32x4 acc0 = {0.f, 0.f, 0.f, 0.f};
  f32x4 acc1 = {0.f, 0.f, 0.f, 0.f};

  {
    *(uint4*)&Kls[0][skey * KSTR + scol] = kreg;
    unsigned int vv[4] = {vreg.x, vreg.y, vreg.z, vreg.w};
    #pragma unroll
    for (int j = 0; j < 4; j++){
      Vls[0][(scol + 2 * j    ) * VSTR + skey] = (unsigned short)(vv[j] & 0xffffu);
      Vls[0][(scol + 2 * j + 1) * VSTR + skey] = (unsigned short)(vv[j] >> 16);
    }
  }

  for (int kt = 0; kt < NCTX / 64; kt++){
    int b = kt & 1;
    __syncthreads();
    if (kt + 1 < NCTX / 64){
      kreg = *(const uint4*)(kbase + (size_t)((kt + 1) * 64 + skey) * 768);
      vreg = *(const uint4*)(kbase + (size_t)((kt + 1) * 64 + skey) * 768 + 256);
    }

    f32x4 s0 = {0.f,0.f,0.f,0.f}, s1 = {0.f,0.f,0.f,0.f};
    f32x4 s2 = {0.f,0.f,0.f,0.f}, s3 = {0.f,0.f,0.f,0.f};
    {
      const short8 k0 = *(const short8*)&Kls[b][( 0 + qr) * KSTR + grp * 8];
      const short8 k1 = *(const short8*)&Kls[b][(16 + qr) * KSTR + grp * 8];
      const short8 k2 = *(const short8*)&Kls[b][(32 + qr) * KSTR + grp * 8];
      const short8 k3 = *(const short8*)&Kls[b][(48 + qr) * KSTR + grp * 8];
      s0 = __builtin_amdgcn_mfma_f32_16x16x32_bf16(k0, qf, s0, 0, 0, 0);
      s1 = __builtin_amdgcn_mfma_f32_16x16x32_bf16(k1, qf, s1, 0, 0, 0);
      s2 = __builtin_amdgcn_mfma_f32_16x16x32_bf16(k2, qf, s2, 0, 0, 0);
      s3 = __builtin_amdgcn_mfma_f32_16x16x32_bf16(k3, qf, s3, 0, 0, 0);
    }

    float sc[4][4];
    #pragma unroll
    for (int r = 0; r < 4; r++){
      sc[0][r] = s0[r] * scale; sc[1][r] = s1[r] * scale;
      sc[2][r] = s2[r] * scale; sc[3][r] = s3[r] * scale;
    }
    float tm = sc[0][0];
    #pragma unroll
    for (int kb = 0; kb < 4; kb++)
      #pragma unroll
      for (int r = 0; r < 4; r++) tm = fmaxf(tm, sc[kb][r]);
    tm = fmaxf(tm, __shfl_xor(tm, 16));
    tm = fmaxf(tm, __shfl_xor(tm, 32));
    float mn = fmaxf(mq, tm);
    float corr = __expf(mq - mn);
    float ts = 0.f;
    float p[4][4];
    #pragma unroll
    for (int kb = 0; kb < 4; kb++)
      #pragma unroll
      for (int r = 0; r < 4; r++){
        float pv = __expf(sc[kb][r] - mn);
        p[kb][r] = pv; ts += pv;
      }
    ts += __shfl_xor(ts, 16);
    ts += __shfl_xor(ts, 32);
    lq = lq * corr + ts;
    mq = mn;
    #pragma unroll
    for (int r = 0; r < 4; r++){ acc0[r] *= corr; acc1[r] *= corr; }

    #pragma unroll
    for (int kb = 0; kb < 4; kb++){
      *(unsigned int*)&Pw[qr * PSTR + kb * 16 + grp * 4]     = pack_bf16x2(p[kb][0], p[kb][1]);
      *(unsigned int*)&Pw[qr * PSTR + kb * 16 + grp * 4 + 2] = pack_bf16x2(p[kb][2], p[kb][3]);
    }

    #pragma unroll
    for (int hh = 0; hh < 2; hh++){
      const short8 pf = *(const short8*)&Pw[qr * PSTR + hh * 32 + grp * 8];
      const short8 v0 = *(const short8*)&Vls[b][( 0 + qr) * VSTR + hh * 32 + grp * 8];
      const short8 v1 = *(const short8*)&Vls[b][(16 + qr) * VSTR + hh * 32 + grp * 8];
      acc0 = __builtin_amdgcn_mfma_f32_16x16x32_bf16(v0, pf, acc0, 0, 0, 0);
      acc1 = __builtin_amdgcn_mfma_f32_16x16x32_bf16(v1, pf, acc1, 0, 0, 0);
    }

    if (kt + 1 < NCTX / 64){
      *(uint4*)&Kls[b ^ 1][skey * KSTR + scol] = kreg;
      unsigned int vv[4] = {vreg.x, vreg.y, vreg.z, vreg.w};
      #pragma unroll
      for (int j = 0; j < 4; j++){
        Vls[b ^ 1][(scol + 2 * j    ) * VSTR + skey] = (unsigned short)(vv[j] & 0xffffu);
        Vls[b ^ 1][(scol + 2 * j + 1) * VSTR + skey] = (unsigned short)(vv[j] >> 16);
      }
    }
  }

  float inv = 1.0f / lq;
  unsigned short* op = ob + ((size_t)(m * NCTX + q0 + qr)) * DMODEL + h * DHEAD;
  uint2 o16a, o16b;
  o16a.x = pack_bf16x2(acc0[0] * inv, acc0[1] * inv);
  o16a.y = pack_bf16x2(acc0[2] * inv, acc0[3] * inv);
  o16b.x = pack_bf16x2(acc1[0] * inv, acc1[1] * inv);
  o16b.y = pack_bf16x2(acc1[2] * inv, acc1[3] * inv);
  *(uint2*)(op + grp * 4)      = o16a;
  *(uint2*)(op + 16 + grp * 4) = o16b;
}

// ---------------- cross-attention over 9 gathered neighbours (bf16 out) -----------
__global__ __launch_bounds__(256)
void ca_attn_kernel(const float* __restrict__ qb, const float* __restrict__ kv,
                    const int* __restrict__ idx, const float* __restrict__ mask,
                    unsigned short* __restrict__ ob){
  int g = blockIdx.x;
  int m = g >> 11;
  int tid = threadIdx.x;
  const float scale = 0.17677669529663687f;
  float q = qb[(size_t)g * DMODEL + tid] * scale;
  float s[KNB];
  int rws[KNB];
  #pragma unroll
  for (int k = 0; k < KNB; k++){
    int row = idx[(size_t)g * KNB + k];
    rws[k] = row;
    float p = q * kv[((size_t)(m * NCTX + row)) * 512 + tid];
    #pragma unroll
    for (int off = 16; off > 0; off >>= 1) p += __shfl_xor(p, off, 32);
    s[k] = (mask[(size_t)g * KNB + k] > 0.5f) ? p : -1e30f;
  }
  float sm = s[0];
  #pragma unroll
  for (int k = 1; k < KNB; k++) sm = fmaxf(sm, s[k]);
  float den = 0.f, w[KNB];
  #pragma unroll
  for (int k = 0; k < KNB; k++){ w[k] = __expf(s[k] - sm); den += w[k]; }
  float inv = 1.0f / den;
  float o = 0.f;
  #pragma unroll
  for (int k = 0; k < KNB; k++)
    o += w[k] * kv[((size_t)(m * NCTX + rws[k])) * 512 + 256 + tid];
  ob[(size_t)g * DMODEL + tid] = (unsigned short)bf16_rne(o * inv);
}

// ---------------- host launcher ----------------
extern "C" void kernel_launch(void* const* d_in, const int* in_sizes, int n_in,
                              void* d_out, int out_size, void* d_ws, size_t ws_size,
                              hipStream_t stream){
  const float* xc      = (const float*)d_in[0];
  const float* zc_in   = (const float*)d_in[1];
  const float* xt      = (const float*)d_in[2];
  const float* zt_in   = (const float*)d_in[3];
  const float* sa_wqkv = (const float*)d_in[4];
  const float* sa_wo   = (const float*)d_in[5];
  const float* sa_ln1  = (const float*)d_in[6];
  const float* sa_ln2  = (const float*)d_in[7];
  const float* sa_w1   = (const float*)d_in[8];
  const float* sa_b1   = (const float*)d_in[9];
  const float* sa_w2   = (const float*)d_in[10];
  const float* sa_b2   = (const float*)d_in[11];
  const float* ca_wq   = (const float*)d_in[12];
  const float* ca_wkv  = (const float*)d_in[13];
  const float* ca_wo   = (const float*)d_in[14];
  const float* ca_lnq  = (const float*)d_in[15];
  const float* ca_lnkv = (const float*)d_in[16];
  const float* ca_ln2  = (const float*)d_in[17];
  const float* ca_w1   = (const float*)d_in[18];
  const float* ca_b1   = (const float*)d_in[19];
  const float* ca_w2   = (const float*)d_in[20];
  const float* ca_b2   = (const float*)d_in[21];

  if (ws_size < (size_t)WS_FLOATS * sizeof(float)) return;
  float* ws    = (float*)d_ws;
  float* zc    = ws + ZC_OFF;
  unsigned short* hb16 = (unsigned short*)(ws + H_OFF);
  float* qkvb  = ws + QKV_OFF;                       // aliased: bf16 qkv / fp32 CA kv / bf16 ffn-mid
  unsigned short* qkv16 = (unsigned short*)qkvb;
  float* qb    = ws + Q_OFF;
  unsigned short* ob16 = (unsigned short*)(ws + O_OFF);
  int*   idxb  = (int*)(ws + IDX_OFF);
  float* maskb = ws + MASK_OFF;
  float* zt    = (float*)d_out;

  copy_kernel<<<RC * DMODEL / 4 / 256, 256, 0, stream>>>(zc_in, zc, RC * DMODEL / 4);
  copy_kernel<<<RT * DMODEL / 4 / 256, 256, 0, stream>>>(zt_in, zt, RT * DMODEL / 4);
  nn_idx_kernel<<<(MB * NTGT) / 256, 256, 0, stream>>>(xc, xt, idxb, maskb);

  for (int l = 0; l < LAYERS; l++){
    // ---------- self-attention block on zc ----------
    ln_kernel<<<RC / 4, 256, 0, stream>>>(zc, sa_ln1 + l * 2 * DMODEL, hb16, RC);
    gemm_mfma<<<dim3(768 / GBN, RC / GBM), 256, 0, stream>>>(
        hb16, sa_wqkv + (size_t)l * DMODEL * 768, nullptr, nullptr, qkv16, RC, DMODEL, 768, 8);
    sa_attn_mfma<<<dim3(NCTX / 64, NHEAD, MB), 256, 0, stream>>>(qkv16, ob16);
    gemm_mfma<<<dim3(DMODEL / GBN, RC / GBM), 256, 0, stream>>>(
        ob16, sa_wo + (size_t)l * DMODEL * DMODEL, nullptr, zc, zc, RC, DMODEL, DMODEL, 4);
    ln_kernel<<<RC / 4, 256, 0, stream>>>(zc, sa_ln2 + l * 2 * DMODEL, hb16, RC);
    gemm_mfma<<<dim3(FF / GBN, RC / GBM), 256, 0, stream>>>(
        hb16, sa_w1 + (size_t)l * DMODEL * FF, sa_b1 + l * FF, nullptr, qkv16, RC, DMODEL, FF, 1 | 2 | 8);
    gemm_mfma<<<dim3(DMODEL / GBN, RC / GBM), 256, 0, stream>>>(
        qkv16, sa_w2 + (size_t)l * FF * DMODEL, sa_b2 + l * DMODEL, zc, zc, RC, FF, DMODEL, 1 | 4);

    // ---------- cross-attention block on zt ----------
    ln_kernel<<<RC / 4, 256, 0, stream>>>(zc, ca_lnkv + l * 2 * DMODEL, hb16, RC);
    gemm_mfma<<<dim3(512 / GBN, RC / GBM), 256, 0, stream>>>(
        hb16, ca_wkv + (size_t)l * DMODEL * 512, nullptr, nullptr, qkvb, RC, DMODEL, 512, 0);
    ln_kernel<<<RT / 4, 256, 0, stream>>>(zt, ca_lnq + l * 2 * DMODEL, hb16, RT);
    gemm_mfma<<<dim3(DMODEL / GBN, RT / GBM), 256, 0, stream>>>(
        hb16, ca_wq + (size_t)l * DMODEL * DMODEL, nullptr, nullptr, qb, RT, DMODEL, DMODEL, 0);
    ca_attn_kernel<<<RT, 256, 0, stream>>>(qb, qkvb, idxb, maskb, ob16);
    gemm_mfma<<<dim3(DMODEL / GBN, RT / GBM), 256, 0, stream>>>(
        ob16, ca_wo + (size_t)l * DMODEL * DMODEL, nullptr, zt, zt, RT, DMODEL, DMODEL, 4);
    ln_kernel<<<RT / 4, 256, 0, stream>>>(zt, ca_ln2 + l * 2 * DMODEL, hb16, RT);
    gemm_mfma<<<dim3(FF / GBN, RT / GBM), 256, 0, stream>>>(
        hb16, ca_w1 + (size_t)l * DMODEL * FF, ca_b1 + l * FF, nullptr, qkv16, RT, DMODEL, FF, 1 | 2 | 8);
    gemm_mfma<<<dim3(DMODEL / GBN, RT / GBM), 256, 0, stream>>>(
        qkv16, ca_w2 + (size_t)l * FF * DMODEL, ca_b2 + l * DMODEL, zt, zt, RT, FF, DMODEL, 1 | 4);
  }
}